// Round 12
// baseline (1085.990 us; speedup 1.0000x reference)
//
#include <hip/hip_runtime.h>

// InteractionBlock: N=50000 nodes, M=32 nbrs, HID=128, FILT=128, NBR=64
//  k0a: node_repr f32 -> bf16 table in d_ws
//  k0b: fw1 -> bf16 transposed table w1T in d_ws (16KB, L1-resident in k1)
//  k1 : fused filter MLP (bf16 MFMA) + block-gather message -> msg (d_out)
//  k2a: u = silu(msg@uw1+ub1) -> bf16 u in d_ws (overwrites node table)
//  k2b: out = u@uw2+ub2 -> d_out
//
// R11 -> R12 (law: dur ~= (FETCH+WRITE)/2.9-3.2 TB/s; R9 was LDS-limited not
// reg-limited (VGPR=128 @ (256,2)); R9 WRITE=120MB = 4.7x amp from 16B-chunk
// masked stores; R11 showed per-wave global re-reads of 32KB w2 are poison
// but 16KB w1 fits L1):
//  * back to R9 structure (best: 452us k1), plus:
//  * msg store via wave-private ft-tile bounce -> all-64-lane f32x2, 512B
//    contiguous full sectors (WRITE 120->27MB, kills store RFO)
//  * w1 out of LDS -> global bf16 table (L1-resident); w2 STAYS in LDS
//    (stride 132). LDS 71.7->51KB -> 3 blocks/CU = 12 waves/CU (+50% occ)
//  * __launch_bounds__(256,3): cap 170 regs (natural ~128, no squeeze)
//
// MFMA layouts (gfx950 16x16, verified m89/m91): A/B x32: row/col=lane&15,
// k=(lane>>4)*8+j; _1k x16: k=(lane>>4)*4+j; C/D: col=lane&15, row=(lane>>4)*4+reg.
// Transposed GEMM2 (A=w2 frag, B=P): lane holds filter[m=c][hid=16ct+4g+q].
// Block-gather: lane (r=l>>3,k=l&7) reads row idx_r, 16B chunk k -> one
// dwordx4 = 8 rows x 128B fully-used lines (two-sided gather law, R6/R7).

#define NN 50000
#define MM 32
#define HID 128
#define NBR 64

typedef __attribute__((ext_vector_type(4))) float f32x4;
typedef __attribute__((ext_vector_type(2))) float f32x2;
typedef __attribute__((ext_vector_type(8))) short s16x8;
typedef __attribute__((ext_vector_type(4))) short s16x4;

__device__ __forceinline__ short f2bf(float x) {
  unsigned u = __builtin_bit_cast(unsigned, x);
  unsigned r = (u + 0x7FFFu + ((u >> 16) & 1u)) >> 16;
  return (short)r;
}

__device__ __forceinline__ float bf2f(short b) {
  return __builtin_bit_cast(float, (unsigned)(unsigned short)b << 16);
}

__device__ __forceinline__ float silu(float x) {
  return x / (1.0f + __expf(-x));
}

// ---------------------------------------------------------------- kernel 0a
__global__ __launch_bounds__(256) void k_cvt_node(
    const float* __restrict__ in, short* __restrict__ out)
{
  int i = blockIdx.x * 256 + threadIdx.x;            // float4 index
  if (i < NN * HID / 4) {
    f32x4 v = *(reinterpret_cast<const f32x4*>(in) + i);
    s16x4 o;
    #pragma unroll
    for (int r = 0; r < 4; ++r) o[r] = f2bf(v[r]);
    reinterpret_cast<s16x4*>(out)[i] = o;
  }
}

// ---------------------------------------------------------------- kernel 0b
// fw1 [64k][128f] -> w1T bf16 [f][64k]
__global__ __launch_bounds__(256) void k_cvt_w(
    const float* __restrict__ fw1, short* __restrict__ w1T)
{
  int tid = blockIdx.x * 256 + threadIdx.x;
  if (tid < 64 * 128) {
    int k = tid >> 7, f = tid & 127;
    w1T[f * 64 + k] = f2bf(fw1[tid]);
  }
}

// ---------------------------------------------------------------- kernel 1
__global__ __launch_bounds__(256, 3) void k_filter_message(
    const short* __restrict__ node_bf, const float* __restrict__ nbr_fea,
    const int* __restrict__ nbr_idx, const short* __restrict__ w1T,
    const float* __restrict__ fw2, const float* __restrict__ fb1,
    const float* __restrict__ fb2, float* __restrict__ msg_out)
{
  __shared__ __align__(16) short s_w2[128 * 132];     // 33.0 KB  fw2T[h][k], stride 132
  __shared__ float s_b1[128];
  __shared__ __align__(16) float s_b2[128];
  __shared__ __align__(16) short s_ft[4][16 * 136];   // 17.0 KB per-wave filter tile
  // total 51.0 KB -> 3 blocks/CU

  const int tid = threadIdx.x;
  for (int i = tid; i < 128 * 128; i += 256) {     // fw2 given [k<128][h<128]
    int k = i >> 7, h = i & 127;
    s_w2[h * 132 + k] = f2bf(fw2[i]);
  }
  if (tid < 128) { s_b1[tid] = fb1[tid]; s_b2[tid] = fb2[tid]; }
  __syncthreads();

  const int wave = tid >> 6, lane = tid & 63;
  const int c = lane & 15, g = lane >> 4;     // MFMA fragment coords
  const int r = lane >> 3, k = lane & 7;      // block-gather coords
  short* __restrict__ ft = s_ft[wave];        // wave-private [16 rows][136]
  const int gw = blockIdx.x * 4 + wave;
  const int STRIDE = 768 * 4;                 // 3072 waves

  // prologue: this node's gather row indices (rows mt*16+8i+r)
  int vidx[2][2];
  #pragma unroll
  for (int mt = 0; mt < 2; ++mt)
    #pragma unroll
    for (int i = 0; i < 2; ++i)
      vidx[mt][i] = nbr_idx[(size_t)gw * MM + mt * 16 + 8 * i + r];

  for (int n = gw; n < NN; n += STRIDE) {
    // 1: issue all 8 block-gather loads NOW (consumed after GEMM2 phases)
    s16x8 gr[2][2][2];   // [mt][i][h]
    #pragma unroll
    for (int mt = 0; mt < 2; ++mt)
      #pragma unroll
      for (int i = 0; i < 2; ++i) {
        const short* rp = node_bf + (size_t)vidx[mt][i] * HID + 8 * k;
        gr[mt][i][0] = *reinterpret_cast<const s16x8*>(rp);
        gr[mt][i][1] = *reinterpret_cast<const s16x8*>(rp + 64);
      }

    // 2: stream nbr_fea (NT) -> B1 frags
    const float* nf = nbr_fea + (size_t)n * (MM * NBR);
    s16x8 b1[2][2];
    #pragma unroll
    for (int mt = 0; mt < 2; ++mt)
      #pragma unroll
      for (int kt = 0; kt < 2; ++kt) {
        const f32x4* src = reinterpret_cast<const f32x4*>(
            nf + (mt * 16 + c) * NBR + kt * 32 + g * 8);
        f32x4 lo = __builtin_nontemporal_load(src);
        f32x4 hi = __builtin_nontemporal_load(src + 1);
        s16x8 v;
        v[0] = f2bf(lo[0]); v[1] = f2bf(lo[1]); v[2] = f2bf(lo[2]); v[3] = f2bf(lo[3]);
        v[4] = f2bf(hi[0]); v[5] = f2bf(hi[1]); v[6] = f2bf(hi[2]); v[7] = f2bf(hi[3]);
        b1[mt][kt] = v;
      }

    // 3: prefetch NEXT node's gather indices
    {
      int n2 = n + STRIDE;
      int np = (n2 < NN) ? n2 : n;
      #pragma unroll
      for (int mt = 0; mt < 2; ++mt)
        #pragma unroll
        for (int i = 0; i < 2; ++i)
          vidx[mt][i] = nbr_idx[(size_t)np * MM + mt * 16 + 8 * i + r];
    }

    // 4: GEMM1 (transposed): h^T = fw1T . nbr^T; w1 frags from GLOBAL (L1)
    s16x4 P[8][2];
    #pragma unroll
    for (int t = 0; t < 8; ++t) {
      f32x4 a0 = f32x4{0.f, 0.f, 0.f, 0.f};
      f32x4 a1 = f32x4{0.f, 0.f, 0.f, 0.f};
      #pragma unroll
      for (int kt = 0; kt < 2; ++kt) {
        s16x8 w1f = *reinterpret_cast<const s16x8*>(
            w1T + (t * 16 + c) * 64 + kt * 32 + g * 8);
        a0 = __builtin_amdgcn_mfma_f32_16x16x32_bf16(w1f, b1[0][kt], a0, 0, 0, 0);
        a1 = __builtin_amdgcn_mfma_f32_16x16x32_bf16(w1f, b1[1][kt], a1, 0, 0, 0);
      }
      s16x4 p0, p1;
      #pragma unroll
      for (int q = 0; q < 4; ++q) {
        float bias = s_b1[t * 16 + g * 4 + q];
        p0[q] = f2bf(silu(a0[q] + bias));
        p1[q] = f2bf(silu(a1[q] + bias));
      }
      P[t][0] = p0;
      P[t][1] = p1;
    }

    // 5/6: per mt-half: GEMM2 (transposed, w2 from LDS) -> bf16 ft tile ->
    //      block-gather FMA
    float part0[8], part1[8];   // partial msg, hid = 8k+j and 64+8k+j
    #pragma unroll
    for (int j = 0; j < 8; ++j) { part0[j] = 0.f; part1[j] = 0.f; }

    #pragma unroll
    for (int mt = 0; mt < 2; ++mt) {
      #pragma unroll
      for (int ct = 0; ct < 8; ++ct) {
        f32x4 t = f32x4{0.f, 0.f, 0.f, 0.f};
        #pragma unroll
        for (int kt = 0; kt < 8; ++kt) {
          s16x4 w2f = *reinterpret_cast<const s16x4*>(
              &s_w2[(ct * 16 + c) * 132 + kt * 16 + g * 4]);
          t = __builtin_amdgcn_mfma_f32_16x16x16bf16_1k(w2f, P[kt][mt], t, 0, 0, 0);
        }
        f32x4 fb = *reinterpret_cast<const f32x4*>(&s_b2[ct * 16 + 4 * g]);
        s16x4 pk;
        #pragma unroll
        for (int q = 0; q < 4; ++q) pk[q] = f2bf(t[q] + fb[q]);
        // lane holds filter[m=mt*16+c][hid=16ct+4g+q] -> tile row c
        *reinterpret_cast<s16x4*>(&ft[c * 136 + ct * 16 + 4 * g]) = pk;
      }
      // block-gather FMA: lane (r,k) reads tile rows 8i+r, chunk k
      #pragma unroll
      for (int i = 0; i < 2; ++i) {
        s16x8 f0 = *reinterpret_cast<const s16x8*>(&ft[(8 * i + r) * 136 + 8 * k]);
        s16x8 f1 = *reinterpret_cast<const s16x8*>(&ft[(8 * i + r) * 136 + 64 + 8 * k]);
        #pragma unroll
        for (int j = 0; j < 8; ++j) {
          part0[j] += bf2f(f0[j]) * bf2f(gr[mt][i][0][j]);
          part1[j] += bf2f(f1[j]) * bf2f(gr[mt][i][1][j]);
        }
      }
    }

    // 7: reduce over r (stride-8 lanes)
    #pragma unroll
    for (int j = 0; j < 8; ++j) {
      part0[j] += __shfl_xor(part0[j], 8);
      part0[j] += __shfl_xor(part0[j], 16);
      part0[j] += __shfl_xor(part0[j], 32);
      part1[j] += __shfl_xor(part1[j], 8);
      part1[j] += __shfl_xor(part1[j], 16);
      part1[j] += __shfl_xor(part1[j], 32);
    }

    // 8: store via ft bounce (tile free; same-wave lgkmcnt ordering):
    //    r==0 lanes deposit f32, then all 64 lanes store f32x2 -> 512B
    //    contiguous full sectors (kills 4.7x write amp)
    {
      float* fb32 = reinterpret_cast<float*>(ft);
      if (r == 0) {
        *reinterpret_cast<f32x4*>(&fb32[8 * k])          = f32x4{part0[0], part0[1], part0[2], part0[3]};
        *reinterpret_cast<f32x4*>(&fb32[8 * k + 4])      = f32x4{part0[4], part0[5], part0[6], part0[7]};
        *reinterpret_cast<f32x4*>(&fb32[64 + 8 * k])     = f32x4{part1[0], part1[1], part1[2], part1[3]};
        *reinterpret_cast<f32x4*>(&fb32[64 + 8 * k + 4]) = f32x4{part1[4], part1[5], part1[6], part1[7]};
      }
      f32x2 mv = *reinterpret_cast<const f32x2*>(&fb32[2 * lane]);
      *reinterpret_cast<f32x2*>(msg_out + (size_t)n * HID + 2 * lane) = mv;
    }
  }
}

// ---------------------------------------------------------------- kernel 2a
// u^T = silu(uw1^T . msg^T + ub1) -> bf16 u[row][128] in ws
__global__ __launch_bounds__(256, 2) void k_update1(
    const float* __restrict__ msg, const float* __restrict__ uw1,
    const float* __restrict__ ub1, short* __restrict__ u_out)
{
  __shared__ __align__(16) short s_w1[128 * 136];   // uw1T[f][k], stride 136
  __shared__ float s_b1[128];
  const int tid = threadIdx.x;
  for (int i = tid; i < 128 * 128; i += 256) {      // uw1 given [k][f]
    int k = i >> 7, f = i & 127;
    s_w1[f * 136 + k] = f2bf(uw1[i]);
  }
  if (tid < 128) s_b1[tid] = ub1[tid];
  __syncthreads();

  const int wave = tid >> 6, lane = tid & 63;
  const int c = lane & 15, g = lane >> 4;
  const long base = (long)(blockIdx.x * 4 + wave) * 32;
  if (base >= NN) return;

  s16x8 bfr[2][4];
  #pragma unroll
  for (int mt = 0; mt < 2; ++mt)
    #pragma unroll
    for (int kt = 0; kt < 4; ++kt) {
      long row = base + mt * 16 + c; if (row > NN - 1) row = NN - 1;
      const float* src = msg + row * HID + kt * 32 + g * 8;
      float4 lo = *reinterpret_cast<const float4*>(src);
      float4 hi = *reinterpret_cast<const float4*>(src + 4);
      s16x8 v;
      v[0] = f2bf(lo.x); v[1] = f2bf(lo.y); v[2] = f2bf(lo.z); v[3] = f2bf(lo.w);
      v[4] = f2bf(hi.x); v[5] = f2bf(hi.y); v[6] = f2bf(hi.z); v[7] = f2bf(hi.w);
      bfr[mt][kt] = v;
    }

  f32x4 acc[8][2];
  #pragma unroll
  for (int t = 0; t < 8; ++t)
    #pragma unroll
    for (int mt = 0; mt < 2; ++mt)
      acc[t][mt] = f32x4{0.f, 0.f, 0.f, 0.f};
  #pragma unroll
  for (int kt = 0; kt < 4; ++kt)
    #pragma unroll
    for (int t = 0; t < 8; ++t) {
      s16x8 a = *reinterpret_cast<const s16x8*>(&s_w1[(t * 16 + c) * 136 + kt * 32 + g * 8]);
      #pragma unroll
      for (int mt = 0; mt < 2; ++mt)
        acc[t][mt] = __builtin_amdgcn_mfma_f32_16x16x32_bf16(a, bfr[mt][kt], acc[t][mt], 0, 0, 0);
    }

  #pragma unroll
  for (int t = 0; t < 8; ++t)
    #pragma unroll
    for (int mt = 0; mt < 2; ++mt) {
      long row = base + mt * 16 + c;
      if (row < NN) {
        s16x4 p;
        #pragma unroll
        for (int q = 0; q < 4; ++q) {
          float x = acc[t][mt][q] + s_b1[t * 16 + g * 4 + q];
          p[q] = f2bf(silu(x));
        }
        *reinterpret_cast<s16x4*>(&u_out[row * HID + t * 16 + g * 4]) = p;
      }
    }
}

// ---------------------------------------------------------------- kernel 2b
// out[m][hid] = u . uw2 + ub2   (16x16x16, A from bf16 u in ws)
__global__ __launch_bounds__(256, 2) void k_update2(
    const short* __restrict__ u, const float* __restrict__ uw2,
    const float* __restrict__ ub2, float* __restrict__ out)
{
  __shared__ __align__(16) short s_w2[128 * 136];   // uw2T[h][k]
  __shared__ float s_b2[128];
  const int tid = threadIdx.x;
  for (int i = tid; i < 128 * 128; i += 256) {      // uw2 given [k][h]
    int k = i >> 7, h = i & 127;
    s_w2[h * 136 + k] = f2bf(uw2[i]);
  }
  if (tid < 128) s_b2[tid] = ub2[tid];
  __syncthreads();

  const int wave = tid >> 6, lane = tid & 63;
  const int c = lane & 15, g = lane >> 4;
  const long base = (long)(blockIdx.x * 4 + wave) * 32;
  if (base >= NN) return;

  s16x4 afr[2][8];
  #pragma unroll
  for (int mt = 0; mt < 2; ++mt)
    #pragma unroll
    for (int kt = 0; kt < 8; ++kt) {
      long row = base + mt * 16 + c; if (row > NN - 1) row = NN - 1;
      afr[mt][kt] = *reinterpret_cast<const s16x4*>(&u[row * HID + kt * 16 + g * 4]);
    }

  f32x4 acc[8][2];
  #pragma unroll
  for (int ct = 0; ct < 8; ++ct)
    #pragma unroll
    for (int mt = 0; mt < 2; ++mt)
      acc[ct][mt] = f32x4{0.f, 0.f, 0.f, 0.f};
  #pragma unroll
  for (int ct = 0; ct < 8; ++ct)
    #pragma unroll
    for (int kt = 0; kt < 8; ++kt) {
      s16x4 b2 = *reinterpret_cast<const s16x4*>(&s_w2[(ct * 16 + c) * 136 + kt * 16 + g * 4]);
      #pragma unroll
      for (int mt = 0; mt < 2; ++mt)
        acc[ct][mt] = __builtin_amdgcn_mfma_f32_16x16x16bf16_1k(afr[mt][kt], b2, acc[ct][mt], 0, 0, 0);
    }

  #pragma unroll
  for (int ct = 0; ct < 8; ++ct) {
    const float bias = s_b2[ct * 16 + c];
    #pragma unroll
    for (int mt = 0; mt < 2; ++mt)
      #pragma unroll
      for (int q = 0; q < 4; ++q) {
        long row = base + mt * 16 + g * 4 + q;
        if (row < NN) out[row * HID + ct * 16 + c] = acc[ct][mt][q] + bias;
      }
  }
}

// ---------------------------------------------------------------- launch
extern "C" void kernel_launch(void* const* d_in, const int* in_sizes, int n_in,
                              void* d_out, int out_size, void* d_ws, size_t ws_size,
                              hipStream_t stream) {
  const float* node_repr = (const float*)d_in[0];
  const float* nbr_fea   = (const float*)d_in[1];
  const int*   nbr_idx   = (const int*)d_in[2];
  const float* fw1 = (const float*)d_in[3];
  const float* fb1 = (const float*)d_in[4];
  const float* fw2 = (const float*)d_in[5];
  const float* fb2 = (const float*)d_in[6];
  const float* uw1 = (const float*)d_in[7];
  const float* ub1 = (const float*)d_in[8];
  const float* uw2 = (const float*)d_in[9];
  const float* ub2 = (const float*)d_in[10];
  float* outp = (float*)d_out;
  short* ws16 = (short*)d_ws;
  // ws: [0, NN*HID) node_bf16 (overwritten by u in k2a); then w1T (64*128)
  short* w1T = ws16 + (size_t)NN * HID;

  k_cvt_node<<<(NN * HID / 4 + 255) / 256, 256, 0, stream>>>(node_repr, ws16);
  k_cvt_w<<<32, 256, 0, stream>>>(fw1, w1T);
  // k1: 768 blocks x 256 thr, 3 blocks/CU (LDS 51KB, VGPR<=170), 12 waves/CU
  k_filter_message<<<768, 256, 0, stream>>>(ws16, nbr_fea, nbr_idx,
                                            w1T, fw2, fb1, fb2, outp);
  const int rowblocks = (NN + 31) / 32;        // 1563
  const int grid2 = (rowblocks + 3) / 4;       // 391
  k_update1<<<grid2, 256, 0, stream>>>(outp, uw1, ub1, ws16);  // u overwrites node_bf16
  k_update2<<<grid2, 256, 0, stream>>>(ws16, uw2, ub2, outp);
}

// Round 13
// 479.952 us; speedup vs baseline: 2.2627x; 2.2627x over previous
//
#include <hip/hip_runtime.h>

// InteractionBlock: N=50000 nodes, M=32 nbrs, HID=128, FILT=128, NBR=64
//  k0 : node_repr f32 -> bf16 table in d_ws
//  k1 : per-node fused filter MLP (bf16 MFMA) + block-gather message -> msg (d_out)
//  k2a: u = silu(msg@uw1+ub1) -> bf16 u in d_ws (reuses k0 region)
//  k2b: out = u@uw2+ub2 -> d_out
//
// R12 -> R13: REVERT to R9 (proven best, 452us k1) + ONE fix.
// Register law (R10/R11/R12 calibration): k1 natural unified-file footprint
// ~190-200 regs; caps 128/168 spill 0.9-1.0GB of scratch. ONLY (256,2) is
// safe. Occupancy is register-bound at 2 waves/SIMD — stop fighting it.
// The single change vs R9: msg store was r==0-masked 16B chunks -> 4.7x
// write amp (WRITE 120MB vs 25.6 logical). Now: deposit partials into the
// idle wave-private ft tile, then all 64 lanes store f32x2 -> 512B fully
// contiguous (complete 64B sectors, no partial-line RMW).
//
// Structure (R9): BLOCK-GATHER lane (r=l>>3,k=l&7) reads row idx_r, 16B
// chunk k -> one dwordx4 = 8 rows x 128B fully-used lines (two-sided gather
// law R6/R7: >=128B/row/instr AND fat per-lane payload). Gathers issued
// before GEMM1 (~600cy MFMA cover). Filters relayout via per-wave bf16 LDS
// tile [16][136]; m-sum via 3 shfl_xor over r.
//
// MFMA layouts (gfx950 16x16, verified m89/m91): A/B x32: row/col=lane&15,
// k=(lane>>4)*8+j; _1k x16: k=(lane>>4)*4+j; C/D: col=lane&15, row=(lane>>4)*4+reg.
// Transposed GEMM2 (A=w2 frag, B=P): lane holds filter[m=c][hid=16ct+4g+q].

#define NN 50000
#define MM 32
#define HID 128
#define NBR 64

typedef __attribute__((ext_vector_type(4))) float f32x4;
typedef __attribute__((ext_vector_type(2))) float f32x2;
typedef __attribute__((ext_vector_type(8))) short s16x8;
typedef __attribute__((ext_vector_type(4))) short s16x4;

__device__ __forceinline__ short f2bf(float x) {
  unsigned u = __builtin_bit_cast(unsigned, x);
  unsigned r = (u + 0x7FFFu + ((u >> 16) & 1u)) >> 16;
  return (short)r;
}

__device__ __forceinline__ float bf2f(short b) {
  return __builtin_bit_cast(float, (unsigned)(unsigned short)b << 16);
}

__device__ __forceinline__ float silu(float x) {
  return x / (1.0f + __expf(-x));
}

// ---------------------------------------------------------------- kernel 0
__global__ __launch_bounds__(256) void k_cvt_node(
    const float* __restrict__ in, short* __restrict__ out)
{
  int i = blockIdx.x * 256 + threadIdx.x;            // float4 index
  if (i < NN * HID / 4) {
    f32x4 v = *(reinterpret_cast<const f32x4*>(in) + i);
    s16x4 o;
    #pragma unroll
    for (int r = 0; r < 4; ++r) o[r] = f2bf(v[r]);
    reinterpret_cast<s16x4*>(out)[i] = o;
  }
}

// ---------------------------------------------------------------- kernel 1
__global__ __launch_bounds__(256, 2) void k_filter_message(
    const short* __restrict__ node_bf, const float* __restrict__ nbr_fea,
    const int* __restrict__ nbr_idx, const float* __restrict__ fw1,
    const float* __restrict__ fb1, const float* __restrict__ fw2,
    const float* __restrict__ fb2, float* __restrict__ msg_out)
{
  __shared__ __align__(16) short s_w1[128 * 72];      // 18.4 KB  fw1T[f][k]
  __shared__ __align__(16) short s_w2[128 * 136];     // 34.8 KB  fw2T[h][k]
  __shared__ float s_b1[128];
  __shared__ __align__(16) float s_b2[128];
  __shared__ __align__(16) short s_ft[4][16 * 136];   // 17.4 KB per-wave filter tile
  // total 71.7 KB -> 2 blocks/CU

  const int tid = threadIdx.x;
  for (int i = tid; i < 64 * 128; i += 256) {      // fw1 given [k<64][f<128]
    int k = i >> 7, f = i & 127;
    s_w1[f * 72 + k] = f2bf(fw1[i]);
  }
  for (int i = tid; i < 128 * 128; i += 256) {     // fw2 given [k<128][h<128]
    int k = i >> 7, h = i & 127;
    s_w2[h * 136 + k] = f2bf(fw2[i]);
  }
  if (tid < 128) { s_b1[tid] = fb1[tid]; s_b2[tid] = fb2[tid]; }
  __syncthreads();

  const int wave = tid >> 6, lane = tid & 63;
  const int c = lane & 15, g = lane >> 4;     // MFMA fragment coords
  const int r = lane >> 3, k = lane & 7;      // block-gather coords
  short* __restrict__ ft = s_ft[wave];        // wave-private [16 rows][136]
  const int gw = blockIdx.x * 4 + wave;
  const int STRIDE = 512 * 4;                 // 2048 waves

  // prologue: this node's gather row indices (rows mt*16+8i+r)
  int vidx[2][2];
  #pragma unroll
  for (int mt = 0; mt < 2; ++mt)
    #pragma unroll
    for (int i = 0; i < 2; ++i)
      vidx[mt][i] = nbr_idx[(size_t)gw * MM + mt * 16 + 8 * i + r];

  for (int n = gw; n < NN; n += STRIDE) {
    // 1: issue all 8 block-gather loads NOW (consumed after GEMM2 phases)
    //    lane (r,k): row vidx[mt][i], bf16 chunk hid = 64h + 8k .. +7
    s16x8 gr[2][2][2];   // [mt][i][h]
    #pragma unroll
    for (int mt = 0; mt < 2; ++mt)
      #pragma unroll
      for (int i = 0; i < 2; ++i) {
        const short* rp = node_bf + (size_t)vidx[mt][i] * HID + 8 * k;
        gr[mt][i][0] = *reinterpret_cast<const s16x8*>(rp);
        gr[mt][i][1] = *reinterpret_cast<const s16x8*>(rp + 64);
      }

    // 2: stream nbr_fea (NT) -> B1 frags
    const float* nf = nbr_fea + (size_t)n * (MM * NBR);
    s16x8 b1[2][2];
    #pragma unroll
    for (int mt = 0; mt < 2; ++mt)
      #pragma unroll
      for (int kt = 0; kt < 2; ++kt) {
        const f32x4* src = reinterpret_cast<const f32x4*>(
            nf + (mt * 16 + c) * NBR + kt * 32 + g * 8);
        f32x4 lo = __builtin_nontemporal_load(src);
        f32x4 hi = __builtin_nontemporal_load(src + 1);
        s16x8 v;
        v[0] = f2bf(lo[0]); v[1] = f2bf(lo[1]); v[2] = f2bf(lo[2]); v[3] = f2bf(lo[3]);
        v[4] = f2bf(hi[0]); v[5] = f2bf(hi[1]); v[6] = f2bf(hi[2]); v[7] = f2bf(hi[3]);
        b1[mt][kt] = v;
      }

    // 3: prefetch NEXT node's gather indices
    {
      int n2 = n + STRIDE;
      int np = (n2 < NN) ? n2 : n;
      #pragma unroll
      for (int mt = 0; mt < 2; ++mt)
        #pragma unroll
        for (int i = 0; i < 2; ++i)
          vidx[mt][i] = nbr_idx[(size_t)np * MM + mt * 16 + 8 * i + r];
    }

    // 4: GEMM1 (transposed): h^T = fw1T . nbr^T; bias+silu -> P frags
    s16x4 P[8][2];
    #pragma unroll
    for (int t = 0; t < 8; ++t) {
      f32x4 a0 = f32x4{0.f, 0.f, 0.f, 0.f};
      f32x4 a1 = f32x4{0.f, 0.f, 0.f, 0.f};
      #pragma unroll
      for (int kt = 0; kt < 2; ++kt) {
        s16x8 w1f = *reinterpret_cast<const s16x8*>(&s_w1[(t * 16 + c) * 72 + kt * 32 + g * 8]);
        a0 = __builtin_amdgcn_mfma_f32_16x16x32_bf16(w1f, b1[0][kt], a0, 0, 0, 0);
        a1 = __builtin_amdgcn_mfma_f32_16x16x32_bf16(w1f, b1[1][kt], a1, 0, 0, 0);
      }
      s16x4 p0, p1;
      #pragma unroll
      for (int q = 0; q < 4; ++q) {
        float bias = s_b1[t * 16 + g * 4 + q];
        p0[q] = f2bf(silu(a0[q] + bias));
        p1[q] = f2bf(silu(a1[q] + bias));
      }
      P[t][0] = p0;
      P[t][1] = p1;
    }

    // 5/6: per mt-half: GEMM2 (transposed) -> bf16 tile -> block-gather FMA
    float part0[8], part1[8];   // partial msg, hid = 8k+j and 64+8k+j
    #pragma unroll
    for (int j = 0; j < 8; ++j) { part0[j] = 0.f; part1[j] = 0.f; }

    #pragma unroll
    for (int mt = 0; mt < 2; ++mt) {
      // filters for rows m = mt*16 + c -> tile row c (full 128 hid, stride 136)
      #pragma unroll
      for (int ct = 0; ct < 8; ++ct) {
        f32x4 t = f32x4{0.f, 0.f, 0.f, 0.f};
        #pragma unroll
        for (int kt = 0; kt < 8; ++kt) {
          s16x4 w2f = *reinterpret_cast<const s16x4*>(&s_w2[(ct * 16 + c) * 136 + kt * 16 + g * 4]);
          t = __builtin_amdgcn_mfma_f32_16x16x16bf16_1k(w2f, P[kt][mt], t, 0, 0, 0);
        }
        f32x4 fb = *reinterpret_cast<const f32x4*>(&s_b2[ct * 16 + 4 * g]);
        s16x4 pk;
        #pragma unroll
        for (int q = 0; q < 4; ++q) pk[q] = f2bf(t[q] + fb[q]);
        *reinterpret_cast<s16x4*>(&ft[c * 136 + ct * 16 + 4 * g]) = pk;
      }
      // block-gather FMA: lane (r,k) handles tile rows 8i+r, chunk k
      #pragma unroll
      for (int i = 0; i < 2; ++i) {
        s16x8 f0 = *reinterpret_cast<const s16x8*>(&ft[(8 * i + r) * 136 + 8 * k]);
        s16x8 f1 = *reinterpret_cast<const s16x8*>(&ft[(8 * i + r) * 136 + 64 + 8 * k]);
        #pragma unroll
        for (int j = 0; j < 8; ++j) {
          part0[j] += bf2f(f0[j]) * bf2f(gr[mt][i][0][j]);
          part1[j] += bf2f(f1[j]) * bf2f(gr[mt][i][1][j]);
        }
      }
    }

    // 7: reduce over r (stride-8 lanes)
    #pragma unroll
    for (int j = 0; j < 8; ++j) {
      part0[j] += __shfl_xor(part0[j], 8);
      part0[j] += __shfl_xor(part0[j], 16);
      part0[j] += __shfl_xor(part0[j], 32);
      part1[j] += __shfl_xor(part1[j], 8);
      part1[j] += __shfl_xor(part1[j], 16);
      part1[j] += __shfl_xor(part1[j], 32);
    }

    // 8: store via ft bounce (tile idle now; same-wave DS ordering is
    //    program-order): r==0 lanes deposit f32, then all 64 lanes store
    //    f32x2 -> 512B fully contiguous (kills the 4.7x write amp)
    {
      float* fb32 = reinterpret_cast<float*>(ft);
      if (r == 0) {
        *reinterpret_cast<f32x4*>(&fb32[8 * k])          = f32x4{part0[0], part0[1], part0[2], part0[3]};
        *reinterpret_cast<f32x4*>(&fb32[8 * k + 4])      = f32x4{part0[4], part0[5], part0[6], part0[7]};
        *reinterpret_cast<f32x4*>(&fb32[64 + 8 * k])     = f32x4{part1[0], part1[1], part1[2], part1[3]};
        *reinterpret_cast<f32x4*>(&fb32[64 + 8 * k + 4]) = f32x4{part1[4], part1[5], part1[6], part1[7]};
      }
      f32x2 mv = *reinterpret_cast<const f32x2*>(&fb32[2 * lane]);
      *reinterpret_cast<f32x2*>(msg_out + (size_t)n * HID + 2 * lane) = mv;
    }
  }
}

// ---------------------------------------------------------------- kernel 2a
// u^T = silu(uw1^T . msg^T + ub1) -> bf16 u[row][128] in ws
__global__ __launch_bounds__(256, 2) void k_update1(
    const float* __restrict__ msg, const float* __restrict__ uw1,
    const float* __restrict__ ub1, short* __restrict__ u_out)
{
  __shared__ __align__(16) short s_w1[128 * 136];   // uw1T[f][k], stride 136
  __shared__ float s_b1[128];
  const int tid = threadIdx.x;
  for (int i = tid; i < 128 * 128; i += 256) {      // uw1 given [k][f]
    int k = i >> 7, f = i & 127;
    s_w1[f * 136 + k] = f2bf(uw1[i]);
  }
  if (tid < 128) s_b1[tid] = ub1[tid];
  __syncthreads();

  const int wave = tid >> 6, lane = tid & 63;
  const int c = lane & 15, g = lane >> 4;
  const long base = (long)(blockIdx.x * 4 + wave) * 32;
  if (base >= NN) return;

  s16x8 bfr[2][4];
  #pragma unroll
  for (int mt = 0; mt < 2; ++mt)
    #pragma unroll
    for (int kt = 0; kt < 4; ++kt) {
      long row = base + mt * 16 + c; if (row > NN - 1) row = NN - 1;
      const float* src = msg + row * HID + kt * 32 + g * 8;
      float4 lo = *reinterpret_cast<const float4*>(src);
      float4 hi = *reinterpret_cast<const float4*>(src + 4);
      s16x8 v;
      v[0] = f2bf(lo.x); v[1] = f2bf(lo.y); v[2] = f2bf(lo.z); v[3] = f2bf(lo.w);
      v[4] = f2bf(hi.x); v[5] = f2bf(hi.y); v[6] = f2bf(hi.z); v[7] = f2bf(hi.w);
      bfr[mt][kt] = v;
    }

  f32x4 acc[8][2];
  #pragma unroll
  for (int t = 0; t < 8; ++t)
    #pragma unroll
    for (int mt = 0; mt < 2; ++mt)
      acc[t][mt] = f32x4{0.f, 0.f, 0.f, 0.f};
  #pragma unroll
  for (int kt = 0; kt < 4; ++kt)
    #pragma unroll
    for (int t = 0; t < 8; ++t) {
      s16x8 a = *reinterpret_cast<const s16x8*>(&s_w1[(t * 16 + c) * 136 + kt * 32 + g * 8]);
      #pragma unroll
      for (int mt = 0; mt < 2; ++mt)
        acc[t][mt] = __builtin_amdgcn_mfma_f32_16x16x32_bf16(a, bfr[mt][kt], acc[t][mt], 0, 0, 0);
    }

  #pragma unroll
  for (int t = 0; t < 8; ++t)
    #pragma unroll
    for (int mt = 0; mt < 2; ++mt) {
      long row = base + mt * 16 + c;
      if (row < NN) {
        s16x4 p;
        #pragma unroll
        for (int q = 0; q < 4; ++q) {
          float x = acc[t][mt][q] + s_b1[t * 16 + g * 4 + q];
          p[q] = f2bf(silu(x));
        }
        *reinterpret_cast<s16x4*>(&u_out[row * HID + t * 16 + g * 4]) = p;
      }
    }
}

// ---------------------------------------------------------------- kernel 2b
// out[m][hid] = u . uw2 + ub2   (16x16x16, A from bf16 u in ws)
__global__ __launch_bounds__(256, 2) void k_update2(
    const short* __restrict__ u, const float* __restrict__ uw2,
    const float* __restrict__ ub2, float* __restrict__ out)
{
  __shared__ __align__(16) short s_w2[128 * 136];   // uw2T[h][k]
  __shared__ float s_b2[128];
  const int tid = threadIdx.x;
  for (int i = tid; i < 128 * 128; i += 256) {      // uw2 given [k][h]
    int k = i >> 7, h = i & 127;
    s_w2[h * 136 + k] = f2bf(uw2[i]);
  }
  if (tid < 128) s_b2[tid] = ub2[tid];
  __syncthreads();

  const int wave = tid >> 6, lane = tid & 63;
  const int c = lane & 15, g = lane >> 4;
  const long base = (long)(blockIdx.x * 4 + wave) * 32;
  if (base >= NN) return;

  s16x4 afr[2][8];
  #pragma unroll
  for (int mt = 0; mt < 2; ++mt)
    #pragma unroll
    for (int kt = 0; kt < 8; ++kt) {
      long row = base + mt * 16 + c; if (row > NN - 1) row = NN - 1;
      afr[mt][kt] = *reinterpret_cast<const s16x4*>(&u[row * HID + kt * 16 + g * 4]);
    }

  f32x4 acc[8][2];
  #pragma unroll
  for (int ct = 0; ct < 8; ++ct)
    #pragma unroll
    for (int mt = 0; mt < 2; ++mt)
      acc[ct][mt] = f32x4{0.f, 0.f, 0.f, 0.f};
  #pragma unroll
  for (int ct = 0; ct < 8; ++ct)
    #pragma unroll
    for (int kt = 0; kt < 8; ++kt) {
      s16x4 b2 = *reinterpret_cast<const s16x4*>(&s_w2[(ct * 16 + c) * 136 + kt * 16 + g * 4]);
      #pragma unroll
      for (int mt = 0; mt < 2; ++mt)
        acc[ct][mt] = __builtin_amdgcn_mfma_f32_16x16x16bf16_1k(afr[mt][kt], b2, acc[ct][mt], 0, 0, 0);
    }

  #pragma unroll
  for (int ct = 0; ct < 8; ++ct) {
    const float bias = s_b2[ct * 16 + c];
    #pragma unroll
    for (int mt = 0; mt < 2; ++mt)
      #pragma unroll
      for (int q = 0; q < 4; ++q) {
        long row = base + mt * 16 + g * 4 + q;
        if (row < NN) out[row * HID + ct * 16 + c] = acc[ct][mt][q] + bias;
      }
  }
}

// ---------------------------------------------------------------- launch
extern "C" void kernel_launch(void* const* d_in, const int* in_sizes, int n_in,
                              void* d_out, int out_size, void* d_ws, size_t ws_size,
                              hipStream_t stream) {
  const float* node_repr = (const float*)d_in[0];
  const float* nbr_fea   = (const float*)d_in[1];
  const int*   nbr_idx   = (const int*)d_in[2];
  const float* fw1 = (const float*)d_in[3];
  const float* fb1 = (const float*)d_in[4];
  const float* fw2 = (const float*)d_in[5];
  const float* fb2 = (const float*)d_in[6];
  const float* uw1 = (const float*)d_in[7];
  const float* ub1 = (const float*)d_in[8];
  const float* uw2 = (const float*)d_in[9];
  const float* ub2 = (const float*)d_in[10];
  float* outp = (float*)d_out;
  short* ws16 = (short*)d_ws;   // 12.8 MB: node_bf16 (k0,k1) then u (k2a,k2b)

  k_cvt_node<<<(NN * HID / 4 + 255) / 256, 256, 0, stream>>>(node_repr, ws16);
  // k1: 512 blocks x 256 thr, 2 blocks/CU (LDS 71.7KB, VGPR cap 256)
  k_filter_message<<<512, 256, 0, stream>>>(ws16, nbr_fea, nbr_idx,
                                            fw1, fb1, fw2, fb2, outp);
  const int rowblocks = (NN + 31) / 32;        // 1563
  const int grid2 = (rowblocks + 3) / 4;       // 391
  k_update1<<<grid2, 256, 0, stream>>>(outp, uw1, ub1, ws16);  // u overwrites node_bf16
  k_update2<<<grid2, 256, 0, stream>>>(ws16, uw2, ub2, outp);
}

// Round 14
// 476.717 us; speedup vs baseline: 2.2781x; 1.0068x over previous
//
#include <hip/hip_runtime.h>

// InteractionBlock: N=50000 nodes, M=32 nbrs, HID=128, FILT=128, NBR=64
//  k0 : node_repr f32 -> bf16 table in d_ws
//  k1 : per-node fused filter MLP (bf16 MFMA) + block-gather message -> msg (d_out)
//  k2a: u = silu(msg@uw1+ub1) -> bf16 u in d_ws (reuses k0 region)
//  k2b: out = u@uw2+ub2 -> d_out
//
// R13 -> R14: revert R13's ft-bounce store (WRITE was invariant ~120MB ->
// masked-store amp theory dead; bounce cost 3%). Back to EXACT R9 (best,
// 452us k1), with ONE change: drop __builtin_nontemporal_load on the
// nbr_fea stream.
// FETCH model that finally fits: nbr 410 + gather 410 (all-miss) + misc 90
// = 910MB vs measured 1300MB; gap == nbr stream x2. Mechanism: the two
// 128B halves of each row are read by two separate NT instructions
// (stride-256 wave pattern); 256B EA granule + NT-no-retention => second
// half re-fetches the granule. Plain loads let the granule sit in L2 ->
// kt=1 hits. Predicted FETCH -> ~0.9GB, k1 -> ~320us.
//
// Register law (R10-R12): k1 natural footprint ~190-200 unified regs; any
// launch-bounds cap below that spills ~1GB scratch. Only (256,2) is safe.
//
// Structure (R9): BLOCK-GATHER lane (r=l>>3,k=l&7) reads row idx_r, 16B
// chunk k -> one dwordx4 = 8 rows x 128B fully-used lines (two-sided gather
// law R6/R7). Gathers issued before GEMM1 (~600cy MFMA cover). Filters
// relayout via per-wave bf16 LDS tile [16][136]; m-sum via 3 shfl_xor over r.
//
// MFMA layouts (gfx950 16x16, verified m89/m91): A/B x32: row/col=lane&15,
// k=(lane>>4)*8+j; _1k x16: k=(lane>>4)*4+j; C/D: col=lane&15, row=(lane>>4)*4+reg.
// Transposed GEMM2 (A=w2 frag, B=P): lane holds filter[m=c][hid=16ct+4g+q].

#define NN 50000
#define MM 32
#define HID 128
#define NBR 64

typedef __attribute__((ext_vector_type(4))) float f32x4;
typedef __attribute__((ext_vector_type(8))) short s16x8;
typedef __attribute__((ext_vector_type(4))) short s16x4;

__device__ __forceinline__ short f2bf(float x) {
  unsigned u = __builtin_bit_cast(unsigned, x);
  unsigned r = (u + 0x7FFFu + ((u >> 16) & 1u)) >> 16;
  return (short)r;
}

__device__ __forceinline__ float bf2f(short b) {
  return __builtin_bit_cast(float, (unsigned)(unsigned short)b << 16);
}

__device__ __forceinline__ float silu(float x) {
  return x / (1.0f + __expf(-x));
}

// ---------------------------------------------------------------- kernel 0
__global__ __launch_bounds__(256) void k_cvt_node(
    const float* __restrict__ in, short* __restrict__ out)
{
  int i = blockIdx.x * 256 + threadIdx.x;            // float4 index
  if (i < NN * HID / 4) {
    f32x4 v = *(reinterpret_cast<const f32x4*>(in) + i);
    s16x4 o;
    #pragma unroll
    for (int r = 0; r < 4; ++r) o[r] = f2bf(v[r]);
    reinterpret_cast<s16x4*>(out)[i] = o;
  }
}

// ---------------------------------------------------------------- kernel 1
__global__ __launch_bounds__(256, 2) void k_filter_message(
    const short* __restrict__ node_bf, const float* __restrict__ nbr_fea,
    const int* __restrict__ nbr_idx, const float* __restrict__ fw1,
    const float* __restrict__ fb1, const float* __restrict__ fw2,
    const float* __restrict__ fb2, float* __restrict__ msg_out)
{
  __shared__ __align__(16) short s_w1[128 * 72];      // 18.4 KB  fw1T[f][k]
  __shared__ __align__(16) short s_w2[128 * 136];     // 34.8 KB  fw2T[h][k]
  __shared__ float s_b1[128];
  __shared__ __align__(16) float s_b2[128];
  __shared__ __align__(16) short s_ft[4][16 * 136];   // 17.4 KB per-wave filter tile
  // total 71.7 KB -> 2 blocks/CU

  const int tid = threadIdx.x;
  for (int i = tid; i < 64 * 128; i += 256) {      // fw1 given [k<64][f<128]
    int k = i >> 7, f = i & 127;
    s_w1[f * 72 + k] = f2bf(fw1[i]);
  }
  for (int i = tid; i < 128 * 128; i += 256) {     // fw2 given [k<128][h<128]
    int k = i >> 7, h = i & 127;
    s_w2[h * 136 + k] = f2bf(fw2[i]);
  }
  if (tid < 128) { s_b1[tid] = fb1[tid]; s_b2[tid] = fb2[tid]; }
  __syncthreads();

  const int wave = tid >> 6, lane = tid & 63;
  const int c = lane & 15, g = lane >> 4;     // MFMA fragment coords
  const int r = lane >> 3, k = lane & 7;      // block-gather coords
  short* __restrict__ ft = s_ft[wave];        // wave-private [16 rows][136]
  const int gw = blockIdx.x * 4 + wave;
  const int STRIDE = 512 * 4;                 // 2048 waves

  // prologue: this node's gather row indices (rows mt*16+8i+r)
  int vidx[2][2];
  #pragma unroll
  for (int mt = 0; mt < 2; ++mt)
    #pragma unroll
    for (int i = 0; i < 2; ++i)
      vidx[mt][i] = nbr_idx[(size_t)gw * MM + mt * 16 + 8 * i + r];

  for (int n = gw; n < NN; n += STRIDE) {
    // 1: issue all 8 block-gather loads NOW (consumed after GEMM2 phases)
    //    lane (r,k): row vidx[mt][i], bf16 chunk hid = 64h + 8k .. +7
    s16x8 gr[2][2][2];   // [mt][i][h]
    #pragma unroll
    for (int mt = 0; mt < 2; ++mt)
      #pragma unroll
      for (int i = 0; i < 2; ++i) {
        const short* rp = node_bf + (size_t)vidx[mt][i] * HID + 8 * k;
        gr[mt][i][0] = *reinterpret_cast<const s16x8*>(rp);
        gr[mt][i][1] = *reinterpret_cast<const s16x8*>(rp + 64);
      }

    // 2: stream nbr_fea (PLAIN loads — NT dropped: let the 256B granule sit
    //    in L2 so the second 128B half-access hits instead of re-fetching)
    const float* nf = nbr_fea + (size_t)n * (MM * NBR);
    s16x8 b1[2][2];
    #pragma unroll
    for (int mt = 0; mt < 2; ++mt)
      #pragma unroll
      for (int kt = 0; kt < 2; ++kt) {
        const f32x4* src = reinterpret_cast<const f32x4*>(
            nf + (mt * 16 + c) * NBR + kt * 32 + g * 8);
        f32x4 lo = src[0];
        f32x4 hi = src[1];
        s16x8 v;
        v[0] = f2bf(lo[0]); v[1] = f2bf(lo[1]); v[2] = f2bf(lo[2]); v[3] = f2bf(lo[3]);
        v[4] = f2bf(hi[0]); v[5] = f2bf(hi[1]); v[6] = f2bf(hi[2]); v[7] = f2bf(hi[3]);
        b1[mt][kt] = v;
      }

    // 3: prefetch NEXT node's gather indices
    {
      int n2 = n + STRIDE;
      int np = (n2 < NN) ? n2 : n;
      #pragma unroll
      for (int mt = 0; mt < 2; ++mt)
        #pragma unroll
        for (int i = 0; i < 2; ++i)
          vidx[mt][i] = nbr_idx[(size_t)np * MM + mt * 16 + 8 * i + r];
    }

    // 4: GEMM1 (transposed): h^T = fw1T . nbr^T; bias+silu -> P frags
    s16x4 P[8][2];
    #pragma unroll
    for (int t = 0; t < 8; ++t) {
      f32x4 a0 = f32x4{0.f, 0.f, 0.f, 0.f};
      f32x4 a1 = f32x4{0.f, 0.f, 0.f, 0.f};
      #pragma unroll
      for (int kt = 0; kt < 2; ++kt) {
        s16x8 w1f = *reinterpret_cast<const s16x8*>(&s_w1[(t * 16 + c) * 72 + kt * 32 + g * 8]);
        a0 = __builtin_amdgcn_mfma_f32_16x16x32_bf16(w1f, b1[0][kt], a0, 0, 0, 0);
        a1 = __builtin_amdgcn_mfma_f32_16x16x32_bf16(w1f, b1[1][kt], a1, 0, 0, 0);
      }
      s16x4 p0, p1;
      #pragma unroll
      for (int q = 0; q < 4; ++q) {
        float bias = s_b1[t * 16 + g * 4 + q];
        p0[q] = f2bf(silu(a0[q] + bias));
        p1[q] = f2bf(silu(a1[q] + bias));
      }
      P[t][0] = p0;
      P[t][1] = p1;
    }

    // 5/6: per mt-half: GEMM2 (transposed) -> bf16 tile -> block-gather FMA
    float part0[8], part1[8];   // partial msg, hid = 8k+j and 64+8k+j
    #pragma unroll
    for (int j = 0; j < 8; ++j) { part0[j] = 0.f; part1[j] = 0.f; }

    #pragma unroll
    for (int mt = 0; mt < 2; ++mt) {
      // filters for rows m = mt*16 + c -> tile row c (full 128 hid, stride 136)
      #pragma unroll
      for (int ct = 0; ct < 8; ++ct) {
        f32x4 t = f32x4{0.f, 0.f, 0.f, 0.f};
        #pragma unroll
        for (int kt = 0; kt < 8; ++kt) {
          s16x4 w2f = *reinterpret_cast<const s16x4*>(&s_w2[(ct * 16 + c) * 136 + kt * 16 + g * 4]);
          t = __builtin_amdgcn_mfma_f32_16x16x16bf16_1k(w2f, P[kt][mt], t, 0, 0, 0);
        }
        f32x4 fb = *reinterpret_cast<const f32x4*>(&s_b2[ct * 16 + 4 * g]);
        s16x4 pk;
        #pragma unroll
        for (int q = 0; q < 4; ++q) pk[q] = f2bf(t[q] + fb[q]);
        *reinterpret_cast<s16x4*>(&ft[c * 136 + ct * 16 + 4 * g]) = pk;
      }
      // block-gather FMA: lane (r,k) handles tile rows 8i+r, chunk k
      #pragma unroll
      for (int i = 0; i < 2; ++i) {
        s16x8 f0 = *reinterpret_cast<const s16x8*>(&ft[(8 * i + r) * 136 + 8 * k]);
        s16x8 f1 = *reinterpret_cast<const s16x8*>(&ft[(8 * i + r) * 136 + 64 + 8 * k]);
        #pragma unroll
        for (int j = 0; j < 8; ++j) {
          part0[j] += bf2f(f0[j]) * bf2f(gr[mt][i][0][j]);
          part1[j] += bf2f(f1[j]) * bf2f(gr[mt][i][1][j]);
        }
      }
    }

    // 7: reduce over r (stride-8 lanes) and store (lanes r==0, 256B spans)
    #pragma unroll
    for (int j = 0; j < 8; ++j) {
      part0[j] += __shfl_xor(part0[j], 8);
      part0[j] += __shfl_xor(part0[j], 16);
      part0[j] += __shfl_xor(part0[j], 32);
      part1[j] += __shfl_xor(part1[j], 8);
      part1[j] += __shfl_xor(part1[j], 16);
      part1[j] += __shfl_xor(part1[j], 32);
    }
    if (r == 0) {
      float* mp = msg_out + (size_t)n * HID + 8 * k;
      *reinterpret_cast<f32x4*>(mp)      = f32x4{part0[0], part0[1], part0[2], part0[3]};
      *reinterpret_cast<f32x4*>(mp + 4)  = f32x4{part0[4], part0[5], part0[6], part0[7]};
      *reinterpret_cast<f32x4*>(mp + 64) = f32x4{part1[0], part1[1], part1[2], part1[3]};
      *reinterpret_cast<f32x4*>(mp + 68) = f32x4{part1[4], part1[5], part1[6], part1[7]};
    }
  }
}

// ---------------------------------------------------------------- kernel 2a
// u^T = silu(uw1^T . msg^T + ub1) -> bf16 u[row][128] in ws
__global__ __launch_bounds__(256, 2) void k_update1(
    const float* __restrict__ msg, const float* __restrict__ uw1,
    const float* __restrict__ ub1, short* __restrict__ u_out)
{
  __shared__ __align__(16) short s_w1[128 * 136];   // uw1T[f][k], stride 136
  __shared__ float s_b1[128];
  const int tid = threadIdx.x;
  for (int i = tid; i < 128 * 128; i += 256) {      // uw1 given [k][f]
    int k = i >> 7, f = i & 127;
    s_w1[f * 136 + k] = f2bf(uw1[i]);
  }
  if (tid < 128) s_b1[tid] = ub1[tid];
  __syncthreads();

  const int wave = tid >> 6, lane = tid & 63;
  const int c = lane & 15, g = lane >> 4;
  const long base = (long)(blockIdx.x * 4 + wave) * 32;
  if (base >= NN) return;

  s16x8 bfr[2][4];
  #pragma unroll
  for (int mt = 0; mt < 2; ++mt)
    #pragma unroll
    for (int kt = 0; kt < 4; ++kt) {
      long row = base + mt * 16 + c; if (row > NN - 1) row = NN - 1;
      const float* src = msg + row * HID + kt * 32 + g * 8;
      float4 lo = *reinterpret_cast<const float4*>(src);
      float4 hi = *reinterpret_cast<const float4*>(src + 4);
      s16x8 v;
      v[0] = f2bf(lo.x); v[1] = f2bf(lo.y); v[2] = f2bf(lo.z); v[3] = f2bf(lo.w);
      v[4] = f2bf(hi.x); v[5] = f2bf(hi.y); v[6] = f2bf(hi.z); v[7] = f2bf(hi.w);
      bfr[mt][kt] = v;
    }

  f32x4 acc[8][2];
  #pragma unroll
  for (int t = 0; t < 8; ++t)
    #pragma unroll
    for (int mt = 0; mt < 2; ++mt)
      acc[t][mt] = f32x4{0.f, 0.f, 0.f, 0.f};
  #pragma unroll
  for (int kt = 0; kt < 4; ++kt)
    #pragma unroll
    for (int t = 0; t < 8; ++t) {
      s16x8 a = *reinterpret_cast<const s16x8*>(&s_w1[(t * 16 + c) * 136 + kt * 32 + g * 8]);
      #pragma unroll
      for (int mt = 0; mt < 2; ++mt)
        acc[t][mt] = __builtin_amdgcn_mfma_f32_16x16x32_bf16(a, bfr[mt][kt], acc[t][mt], 0, 0, 0);
    }

  #pragma unroll
  for (int t = 0; t < 8; ++t)
    #pragma unroll
    for (int mt = 0; mt < 2; ++mt) {
      long row = base + mt * 16 + c;
      if (row < NN) {
        s16x4 p;
        #pragma unroll
        for (int q = 0; q < 4; ++q) {
          float x = acc[t][mt][q] + s_b1[t * 16 + g * 4 + q];
          p[q] = f2bf(silu(x));
        }
        *reinterpret_cast<s16x4*>(&u_out[row * HID + t * 16 + g * 4]) = p;
      }
    }
}

// ---------------------------------------------------------------- kernel 2b
// out[m][hid] = u . uw2 + ub2   (16x16x16, A from bf16 u in ws)
__global__ __launch_bounds__(256, 2) void k_update2(
    const short* __restrict__ u, const float* __restrict__ uw2,
    const float* __restrict__ ub2, float* __restrict__ out)
{
  __shared__ __align__(16) short s_w2[128 * 136];   // uw2T[h][k]
  __shared__ float s_b2[128];
  const int tid = threadIdx.x;
  for (int i = tid; i < 128 * 128; i += 256) {      // uw2 given [k][h]
    int k = i >> 7, h = i & 127;
    s_w2[h * 136 + k] = f2bf(uw2[i]);
  }
  if (tid < 128) s_b2[tid] = ub2[tid];
  __syncthreads();

  const int wave = tid >> 6, lane = tid & 63;
  const int c = lane & 15, g = lane >> 4;
  const long base = (long)(blockIdx.x * 4 + wave) * 32;
  if (base >= NN) return;

  s16x4 afr[2][8];
  #pragma unroll
  for (int mt = 0; mt < 2; ++mt)
    #pragma unroll
    for (int kt = 0; kt < 8; ++kt) {
      long row = base + mt * 16 + c; if (row > NN - 1) row = NN - 1;
      afr[mt][kt] = *reinterpret_cast<const s16x4*>(&u[row * HID + kt * 16 + g * 4]);
    }

  f32x4 acc[8][2];
  #pragma unroll
  for (int ct = 0; ct < 8; ++ct)
    #pragma unroll
    for (int mt = 0; mt < 2; ++mt)
      acc[ct][mt] = f32x4{0.f, 0.f, 0.f, 0.f};
  #pragma unroll
  for (int ct = 0; ct < 8; ++ct)
    #pragma unroll
    for (int kt = 0; kt < 8; ++kt) {
      s16x4 b2 = *reinterpret_cast<const s16x4*>(&s_w2[(ct * 16 + c) * 136 + kt * 16 + g * 4]);
      #pragma unroll
      for (int mt = 0; mt < 2; ++mt)
        acc[ct][mt] = __builtin_amdgcn_mfma_f32_16x16x16bf16_1k(afr[mt][kt], b2, acc[ct][mt], 0, 0, 0);
    }

  #pragma unroll
  for (int ct = 0; ct < 8; ++ct) {
    const float bias = s_b2[ct * 16 + c];
    #pragma unroll
    for (int mt = 0; mt < 2; ++mt)
      #pragma unroll
      for (int q = 0; q < 4; ++q) {
        long row = base + mt * 16 + g * 4 + q;
        if (row < NN) out[row * HID + ct * 16 + c] = acc[ct][mt][q] + bias;
      }
  }
}

// ---------------------------------------------------------------- launch
extern "C" void kernel_launch(void* const* d_in, const int* in_sizes, int n_in,
                              void* d_out, int out_size, void* d_ws, size_t ws_size,
                              hipStream_t stream) {
  const float* node_repr = (const float*)d_in[0];
  const float* nbr_fea   = (const float*)d_in[1];
  const int*   nbr_idx   = (const int*)d_in[2];
  const float* fw1 = (const float*)d_in[3];
  const float* fb1 = (const float*)d_in[4];
  const float* fw2 = (const float*)d_in[5];
  const float* fb2 = (const float*)d_in[6];
  const float* uw1 = (const float*)d_in[7];
  const float* ub1 = (const float*)d_in[8];
  const float* uw2 = (const float*)d_in[9];
  const float* ub2 = (const float*)d_in[10];
  float* outp = (float*)d_out;
  short* ws16 = (short*)d_ws;   // 12.8 MB: node_bf16 (k0,k1) then u (k2a,k2b)

  k_cvt_node<<<(NN * HID / 4 + 255) / 256, 256, 0, stream>>>(node_repr, ws16);
  // k1: 512 blocks x 256 thr, 2 blocks/CU (LDS 71.7KB, VGPR cap 256)
  k_filter_message<<<512, 256, 0, stream>>>(ws16, nbr_fea, nbr_idx,
                                            fw1, fb1, fw2, fb2, outp);
  const int rowblocks = (NN + 31) / 32;        // 1563
  const int grid2 = (rowblocks + 3) / 4;       // 391
  k_update1<<<grid2, 256, 0, stream>>>(outp, uw1, ub1, ws16);  // u overwrites node_bf16
  k_update2<<<grid2, 256, 0, stream>>>(ws16, uw2, ub2, outp);
}

// Round 15
// 467.108 us; speedup vs baseline: 2.3249x; 1.0206x over previous
//
#include <hip/hip_runtime.h>

// InteractionBlock: N=50000 nodes, M=32 nbrs, HID=128, FILT=128, NBR=64
//  k0 : node_repr f32 -> bf16 table in d_ws
//  k1 : per-node fused filter MLP (bf16 MFMA) + block-gather message -> msg (d_out)
//  k2a: u = silu(msg@uw1+ub1) -> bf16 u in d_ws (reuses k0 region)
//  k2b: out = u@uw2+ub2 -> d_out
//
// R14 -> R15: REVERT to R9 verbatim — the measured optimum (466us total,
// 452us k1). Ledger of failed levers (all A/B'd against R9):
//  * occupancy: register-bound at 2 waves/SIMD; natural footprint ~190-200
//    unified regs; launch-bounds caps 128/168 spill ~1GB scratch (R10-R12).
//  * FETCH: invariant 1.25GB = stream 410MB + gather 2x410MB + misc. The
//    gather 2x is granule-fixed (>=512B effective fetch vs random 256B rows):
//    unchanged by NT flags (R14, bit-identical FETCH), store patterns (R13),
//    or access shape. fp8 table would halve it but breaks error budget.
//  * WRITE ~120MB invariant to store contiguity (R13).
//  * pipelining: compiler already optimal (R5 regressed).
// At the measured ~2.9TB/s effective BW for this stream+random-gather mix,
// 1.28GB => ~450us: k1 is at its effective-bandwidth roofline.
//
// Structure (R9): BLOCK-GATHER lane (r=l>>3,k=l&7) reads row idx_r, 16B
// chunk k -> one dwordx4 = 8 rows x 128B fully-used lines (two-sided gather
// law R6/R7: >=128B/row/instr AND fat per-lane payload). Gathers issued
// before GEMM1 (~600cy MFMA cover). Filters relayout via per-wave bf16 LDS
// tile [16][136]; m-sum via 3 shfl_xor over r; r==0 lanes store 256B spans.
//
// MFMA layouts (gfx950 16x16, verified m89/m91): A/B x32: row/col=lane&15,
// k=(lane>>4)*8+j; _1k x16: k=(lane>>4)*4+j; C/D: col=lane&15, row=(lane>>4)*4+reg.
// Transposed GEMM2 (A=w2 frag, B=P): lane holds filter[m=c][hid=16ct+4g+q].

#define NN 50000
#define MM 32
#define HID 128
#define NBR 64

typedef __attribute__((ext_vector_type(4))) float f32x4;
typedef __attribute__((ext_vector_type(8))) short s16x8;
typedef __attribute__((ext_vector_type(4))) short s16x4;

__device__ __forceinline__ short f2bf(float x) {
  unsigned u = __builtin_bit_cast(unsigned, x);
  unsigned r = (u + 0x7FFFu + ((u >> 16) & 1u)) >> 16;
  return (short)r;
}

__device__ __forceinline__ float bf2f(short b) {
  return __builtin_bit_cast(float, (unsigned)(unsigned short)b << 16);
}

__device__ __forceinline__ float silu(float x) {
  return x / (1.0f + __expf(-x));
}

// ---------------------------------------------------------------- kernel 0
__global__ __launch_bounds__(256) void k_cvt_node(
    const float* __restrict__ in, short* __restrict__ out)
{
  int i = blockIdx.x * 256 + threadIdx.x;            // float4 index
  if (i < NN * HID / 4) {
    f32x4 v = *(reinterpret_cast<const f32x4*>(in) + i);
    s16x4 o;
    #pragma unroll
    for (int r = 0; r < 4; ++r) o[r] = f2bf(v[r]);
    reinterpret_cast<s16x4*>(out)[i] = o;
  }
}

// ---------------------------------------------------------------- kernel 1
__global__ __launch_bounds__(256, 2) void k_filter_message(
    const short* __restrict__ node_bf, const float* __restrict__ nbr_fea,
    const int* __restrict__ nbr_idx, const float* __restrict__ fw1,
    const float* __restrict__ fb1, const float* __restrict__ fw2,
    const float* __restrict__ fb2, float* __restrict__ msg_out)
{
  __shared__ __align__(16) short s_w1[128 * 72];      // 18.4 KB  fw1T[f][k]
  __shared__ __align__(16) short s_w2[128 * 136];     // 34.8 KB  fw2T[h][k]
  __shared__ float s_b1[128];
  __shared__ __align__(16) float s_b2[128];
  __shared__ __align__(16) short s_ft[4][16 * 136];   // 17.4 KB per-wave filter tile
  // total 71.7 KB -> 2 blocks/CU

  const int tid = threadIdx.x;
  for (int i = tid; i < 64 * 128; i += 256) {      // fw1 given [k<64][f<128]
    int k = i >> 7, f = i & 127;
    s_w1[f * 72 + k] = f2bf(fw1[i]);
  }
  for (int i = tid; i < 128 * 128; i += 256) {     // fw2 given [k<128][h<128]
    int k = i >> 7, h = i & 127;
    s_w2[h * 136 + k] = f2bf(fw2[i]);
  }
  if (tid < 128) { s_b1[tid] = fb1[tid]; s_b2[tid] = fb2[tid]; }
  __syncthreads();

  const int wave = tid >> 6, lane = tid & 63;
  const int c = lane & 15, g = lane >> 4;     // MFMA fragment coords
  const int r = lane >> 3, k = lane & 7;      // block-gather coords
  short* __restrict__ ft = s_ft[wave];        // wave-private [16 rows][136]
  const int gw = blockIdx.x * 4 + wave;
  const int STRIDE = 512 * 4;                 // 2048 waves

  // prologue: this node's gather row indices, vector form (rows mt*16+8i+r)
  int vidx[2][2];
  #pragma unroll
  for (int mt = 0; mt < 2; ++mt)
    #pragma unroll
    for (int i = 0; i < 2; ++i)
      vidx[mt][i] = nbr_idx[(size_t)gw * MM + mt * 16 + 8 * i + r];

  for (int n = gw; n < NN; n += STRIDE) {
    // 1: issue all 8 block-gather loads NOW (consumed after GEMM2 phases)
    //    lane (r,k): row vidx[mt][i], bf16 chunk hid = 64h + 8k .. +7
    s16x8 gr[2][2][2];   // [mt][i][h]
    #pragma unroll
    for (int mt = 0; mt < 2; ++mt)
      #pragma unroll
      for (int i = 0; i < 2; ++i) {
        const short* rp = node_bf + (size_t)vidx[mt][i] * HID + 8 * k;
        gr[mt][i][0] = *reinterpret_cast<const s16x8*>(rp);
        gr[mt][i][1] = *reinterpret_cast<const s16x8*>(rp + 64);
      }

    // 2: stream nbr_fea (NT) -> B1 frags
    const float* nf = nbr_fea + (size_t)n * (MM * NBR);
    s16x8 b1[2][2];
    #pragma unroll
    for (int mt = 0; mt < 2; ++mt)
      #pragma unroll
      for (int kt = 0; kt < 2; ++kt) {
        const f32x4* src = reinterpret_cast<const f32x4*>(
            nf + (mt * 16 + c) * NBR + kt * 32 + g * 8);
        f32x4 lo = __builtin_nontemporal_load(src);
        f32x4 hi = __builtin_nontemporal_load(src + 1);
        s16x8 v;
        v[0] = f2bf(lo[0]); v[1] = f2bf(lo[1]); v[2] = f2bf(lo[2]); v[3] = f2bf(lo[3]);
        v[4] = f2bf(hi[0]); v[5] = f2bf(hi[1]); v[6] = f2bf(hi[2]); v[7] = f2bf(hi[3]);
        b1[mt][kt] = v;
      }

    // 3: prefetch NEXT node's gather indices
    {
      int n2 = n + STRIDE;
      int np = (n2 < NN) ? n2 : n;
      #pragma unroll
      for (int mt = 0; mt < 2; ++mt)
        #pragma unroll
        for (int i = 0; i < 2; ++i)
          vidx[mt][i] = nbr_idx[(size_t)np * MM + mt * 16 + 8 * i + r];
    }

    // 4: GEMM1 (transposed): h^T = fw1T . nbr^T; bias+silu -> P frags
    s16x4 P[8][2];
    #pragma unroll
    for (int t = 0; t < 8; ++t) {
      f32x4 a0 = f32x4{0.f, 0.f, 0.f, 0.f};
      f32x4 a1 = f32x4{0.f, 0.f, 0.f, 0.f};
      #pragma unroll
      for (int kt = 0; kt < 2; ++kt) {
        s16x8 w1f = *reinterpret_cast<const s16x8*>(&s_w1[(t * 16 + c) * 72 + kt * 32 + g * 8]);
        a0 = __builtin_amdgcn_mfma_f32_16x16x32_bf16(w1f, b1[0][kt], a0, 0, 0, 0);
        a1 = __builtin_amdgcn_mfma_f32_16x16x32_bf16(w1f, b1[1][kt], a1, 0, 0, 0);
      }
      s16x4 p0, p1;
      #pragma unroll
      for (int q = 0; q < 4; ++q) {
        float bias = s_b1[t * 16 + g * 4 + q];
        p0[q] = f2bf(silu(a0[q] + bias));
        p1[q] = f2bf(silu(a1[q] + bias));
      }
      P[t][0] = p0;
      P[t][1] = p1;
    }

    // 5/6: per mt-half: GEMM2 (transposed) -> bf16 tile -> block-gather FMA
    float part0[8], part1[8];   // partial msg, hid = 8k+j and 64+8k+j
    #pragma unroll
    for (int j = 0; j < 8; ++j) { part0[j] = 0.f; part1[j] = 0.f; }

    #pragma unroll
    for (int mt = 0; mt < 2; ++mt) {
      // filters for rows m = mt*16 + c -> tile row c (full 128 hid, stride 136)
      #pragma unroll
      for (int ct = 0; ct < 8; ++ct) {
        f32x4 t = f32x4{0.f, 0.f, 0.f, 0.f};
        #pragma unroll
        for (int kt = 0; kt < 8; ++kt) {
          s16x4 w2f = *reinterpret_cast<const s16x4*>(&s_w2[(ct * 16 + c) * 136 + kt * 16 + g * 4]);
          t = __builtin_amdgcn_mfma_f32_16x16x16bf16_1k(w2f, P[kt][mt], t, 0, 0, 0);
        }
        f32x4 fb = *reinterpret_cast<const f32x4*>(&s_b2[ct * 16 + 4 * g]);
        s16x4 pk;
        #pragma unroll
        for (int q = 0; q < 4; ++q) pk[q] = f2bf(t[q] + fb[q]);
        *reinterpret_cast<s16x4*>(&ft[c * 136 + ct * 16 + 4 * g]) = pk;
      }
      // block-gather FMA: lane (r,k) handles tile rows 8i+r, chunk k
      #pragma unroll
      for (int i = 0; i < 2; ++i) {
        s16x8 f0 = *reinterpret_cast<const s16x8*>(&ft[(8 * i + r) * 136 + 8 * k]);
        s16x8 f1 = *reinterpret_cast<const s16x8*>(&ft[(8 * i + r) * 136 + 64 + 8 * k]);
        #pragma unroll
        for (int j = 0; j < 8; ++j) {
          part0[j] += bf2f(f0[j]) * bf2f(gr[mt][i][0][j]);
          part1[j] += bf2f(f1[j]) * bf2f(gr[mt][i][1][j]);
        }
      }
    }

    // 7: reduce over r (stride-8 lanes) and store (lanes r==0, 256B spans)
    #pragma unroll
    for (int j = 0; j < 8; ++j) {
      part0[j] += __shfl_xor(part0[j], 8);
      part0[j] += __shfl_xor(part0[j], 16);
      part0[j] += __shfl_xor(part0[j], 32);
      part1[j] += __shfl_xor(part1[j], 8);
      part1[j] += __shfl_xor(part1[j], 16);
      part1[j] += __shfl_xor(part1[j], 32);
    }
    if (r == 0) {
      float* mp = msg_out + (size_t)n * HID + 8 * k;
      *reinterpret_cast<f32x4*>(mp)      = f32x4{part0[0], part0[1], part0[2], part0[3]};
      *reinterpret_cast<f32x4*>(mp + 4)  = f32x4{part0[4], part0[5], part0[6], part0[7]};
      *reinterpret_cast<f32x4*>(mp + 64) = f32x4{part1[0], part1[1], part1[2], part1[3]};
      *reinterpret_cast<f32x4*>(mp + 68) = f32x4{part1[4], part1[5], part1[6], part1[7]};
    }
  }
}

// ---------------------------------------------------------------- kernel 2a
// u^T = silu(uw1^T . msg^T + ub1) -> bf16 u[row][128] in ws
__global__ __launch_bounds__(256, 2) void k_update1(
    const float* __restrict__ msg, const float* __restrict__ uw1,
    const float* __restrict__ ub1, short* __restrict__ u_out)
{
  __shared__ __align__(16) short s_w1[128 * 136];   // uw1T[f][k], stride 136
  __shared__ float s_b1[128];
  const int tid = threadIdx.x;
  for (int i = tid; i < 128 * 128; i += 256) {      // uw1 given [k][f]
    int k = i >> 7, f = i & 127;
    s_w1[f * 136 + k] = f2bf(uw1[i]);
  }
  if (tid < 128) s_b1[tid] = ub1[tid];
  __syncthreads();

  const int wave = tid >> 6, lane = tid & 63;
  const int c = lane & 15, g = lane >> 4;
  const long base = (long)(blockIdx.x * 4 + wave) * 32;
  if (base >= NN) return;

  s16x8 bfr[2][4];
  #pragma unroll
  for (int mt = 0; mt < 2; ++mt)
    #pragma unroll
    for (int kt = 0; kt < 4; ++kt) {
      long row = base + mt * 16 + c; if (row > NN - 1) row = NN - 1;
      const float* src = msg + row * HID + kt * 32 + g * 8;
      float4 lo = *reinterpret_cast<const float4*>(src);
      float4 hi = *reinterpret_cast<const float4*>(src + 4);
      s16x8 v;
      v[0] = f2bf(lo.x); v[1] = f2bf(lo.y); v[2] = f2bf(lo.z); v[3] = f2bf(lo.w);
      v[4] = f2bf(hi.x); v[5] = f2bf(hi.y); v[6] = f2bf(hi.z); v[7] = f2bf(hi.w);
      bfr[mt][kt] = v;
    }

  f32x4 acc[8][2];
  #pragma unroll
  for (int t = 0; t < 8; ++t)
    #pragma unroll
    for (int mt = 0; mt < 2; ++mt)
      acc[t][mt] = f32x4{0.f, 0.f, 0.f, 0.f};
  #pragma unroll
  for (int kt = 0; kt < 4; ++kt)
    #pragma unroll
    for (int t = 0; t < 8; ++t) {
      s16x8 a = *reinterpret_cast<const s16x8*>(&s_w1[(t * 16 + c) * 136 + kt * 32 + g * 8]);
      #pragma unroll
      for (int mt = 0; mt < 2; ++mt)
        acc[t][mt] = __builtin_amdgcn_mfma_f32_16x16x32_bf16(a, bfr[mt][kt], acc[t][mt], 0, 0, 0);
    }

  #pragma unroll
  for (int t = 0; t < 8; ++t)
    #pragma unroll
    for (int mt = 0; mt < 2; ++mt) {
      long row = base + mt * 16 + c;
      if (row < NN) {
        s16x4 p;
        #pragma unroll
        for (int q = 0; q < 4; ++q) {
          float x = acc[t][mt][q] + s_b1[t * 16 + g * 4 + q];
          p[q] = f2bf(silu(x));
        }
        *reinterpret_cast<s16x4*>(&u_out[row * HID + t * 16 + g * 4]) = p;
      }
    }
}

// ---------------------------------------------------------------- kernel 2b
// out[m][hid] = u . uw2 + ub2   (16x16x16, A from bf16 u in ws)
__global__ __launch_bounds__(256, 2) void k_update2(
    const short* __restrict__ u, const float* __restrict__ uw2,
    const float* __restrict__ ub2, float* __restrict__ out)
{
  __shared__ __align__(16) short s_w2[128 * 136];   // uw2T[h][k]
  __shared__ float s_b2[128];
  const int tid = threadIdx.x;
  for (int i = tid; i < 128 * 128; i += 256) {      // uw2 given [k][h]
    int k = i >> 7, h = i & 127;
    s_w2[h * 136 + k] = f2bf(uw2[i]);
  }
  if (tid < 128) s_b2[tid] = ub2[tid];
  __syncthreads();

  const int wave = tid >> 6, lane = tid & 63;
  const int c = lane & 15, g = lane >> 4;
  const long base = (long)(blockIdx.x * 4 + wave) * 32;
  if (base >= NN) return;

  s16x4 afr[2][8];
  #pragma unroll
  for (int mt = 0; mt < 2; ++mt)
    #pragma unroll
    for (int kt = 0; kt < 8; ++kt) {
      long row = base + mt * 16 + c; if (row > NN - 1) row = NN - 1;
      afr[mt][kt] = *reinterpret_cast<const s16x4*>(&u[row * HID + kt * 16 + g * 4]);
    }

  f32x4 acc[8][2];
  #pragma unroll
  for (int ct = 0; ct < 8; ++ct)
    #pragma unroll
    for (int mt = 0; mt < 2; ++mt)
      acc[ct][mt] = f32x4{0.f, 0.f, 0.f, 0.f};
  #pragma unroll
  for (int ct = 0; ct < 8; ++ct)
    #pragma unroll
    for (int kt = 0; kt < 8; ++kt) {
      s16x4 b2 = *reinterpret_cast<const s16x4*>(&s_w2[(ct * 16 + c) * 136 + kt * 16 + g * 4]);
      #pragma unroll
      for (int mt = 0; mt < 2; ++mt)
        acc[ct][mt] = __builtin_amdgcn_mfma_f32_16x16x16bf16_1k(afr[mt][kt], b2, acc[ct][mt], 0, 0, 0);
    }

  #pragma unroll
  for (int ct = 0; ct < 8; ++ct) {
    const float bias = s_b2[ct * 16 + c];
    #pragma unroll
    for (int mt = 0; mt < 2; ++mt)
      #pragma unroll
      for (int q = 0; q < 4; ++q) {
        long row = base + mt * 16 + g * 4 + q;
        if (row < NN) out[row * HID + ct * 16 + c] = acc[ct][mt][q] + bias;
      }
  }
}

// ---------------------------------------------------------------- launch
extern "C" void kernel_launch(void* const* d_in, const int* in_sizes, int n_in,
                              void* d_out, int out_size, void* d_ws, size_t ws_size,
                              hipStream_t stream) {
  const float* node_repr = (const float*)d_in[0];
  const float* nbr_fea   = (const float*)d_in[1];
  const int*   nbr_idx   = (const int*)d_in[2];
  const float* fw1 = (const float*)d_in[3];
  const float* fb1 = (const float*)d_in[4];
  const float* fw2 = (const float*)d_in[5];
  const float* fb2 = (const float*)d_in[6];
  const float* uw1 = (const float*)d_in[7];
  const float* ub1 = (const float*)d_in[8];
  const float* uw2 = (const float*)d_in[9];
  const float* ub2 = (const float*)d_in[10];
  float* outp = (float*)d_out;
  short* ws16 = (short*)d_ws;   // 12.8 MB: node_bf16 (k0,k1) then u (k2a,k2b)

  k_cvt_node<<<(NN * HID / 4 + 255) / 256, 256, 0, stream>>>(node_repr, ws16);
  // k1: 512 blocks x 256 thr, 2 blocks/CU (LDS 71.7KB, VGPR cap 256)
  k_filter_message<<<512, 256, 0, stream>>>(ws16, nbr_fea, nbr_idx,
                                            fw1, fb1, fw2, fb2, outp);
  const int rowblocks = (NN + 31) / 32;        // 1563
  const int grid2 = (rowblocks + 3) / 4;       // 391
  k_update1<<<grid2, 256, 0, stream>>>(outp, uw1, ub1, ws16);  // u overwrites node_bf16
  k_update2<<<grid2, 256, 0, stream>>>(ws16, uw2, ub2, outp);
}